// Round 6
// baseline (821.599 us; speedup 1.0000x reference)
//
#include <hip/hip_runtime.h>
#include <hip/hip_bf16.h>

#define N_NODES 50000
#define N_EDGES 500000
#define NBLK_E  1024

// scales
#define S32        0.17677669529663687f   // 1/sqrt(32)
#define INV_SQRT3  0.5773502691896258f
#define WSCALE     0.03952847075210474f   // (1/8 from /sqrt(64)) * (1/sqrt(10))

// ---------------------------------------------------------------------------
// Kernel B: node pre-pass.  f = fctp(x, W_lin1) -> bf16 into d_out[0:12.8MB].
// Row layout (128): [0:32] = f0[w], [32 + m*32 + w] = f1[w][m]  (m-major!)
// ---------------------------------------------------------------------------
__global__ __launch_bounds__(256) void node_pre_kernel(
    const float* __restrict__ node_input, const float* __restrict__ node_attr,
    const float* __restrict__ Wl0,  const float* __restrict__ Wl1,
    __hip_bfloat16* __restrict__ fbf)
{
    __shared__ float w_l0[1024], w_l1[1024];
    __shared__ float xs[8 * 128];
    int t = threadIdx.x;
    for (int i = t; i < 1024; i += 256) { w_l0[i] = Wl0[i]; w_l1[i] = Wl1[i]; }
    int base = blockIdx.x * 8;
    for (int i = t; i < 1024; i += 256) xs[i] = node_input[(size_t)base * 128 + i];
    __syncthreads();

    int nl = t >> 5, w = t & 31;
    int n = base + nl;
    const float* xr = &xs[nl * 128];
    float f0 = 0.f, f1[3] = {0.f, 0.f, 0.f};
    #pragma unroll
    for (int u = 0; u < 32; ++u) {
        float wl0 = w_l0[u * 32 + w], wl1 = w_l1[u * 32 + w];
        f0 += xr[u] * wl0;
        #pragma unroll
        for (int m = 0; m < 3; ++m) f1[m] += xr[32 + u * 3 + m] * wl1;
    }
    float as = node_attr[n] * S32;
    fbf[(size_t)n * 128 + w] = __float2bfloat16(f0 * as);
    #pragma unroll
    for (int m = 0; m < 3; ++m)
        fbf[(size_t)n * 128 + 32 + m * 32 + w] = __float2bfloat16(f1[m] * as);
}

// ---------------------------------------------------------------------------
// Kernel C: fused edge pass. One wave processes 4 edges per iteration:
//   MLP (W_fc2 columns in registers), gather f[src] (bf16), compute 256
//   edge features, atomicAdd into mid[dst].  Wave-synchronous LDS only.
// mid row (256): [0:32]=eA, [32:64]=eD, [64:160]=eB flat, [160:256]=eC flat
// ---------------------------------------------------------------------------
__global__ __launch_bounds__(256) void edge_kernel(
    const float* __restrict__ edge_scalars, const float* __restrict__ edge_attr,
    const int* __restrict__ edge_src, const int* __restrict__ edge_dst,
    const float* __restrict__ Wfc1, const float* __restrict__ Wfc2,
    const __hip_bfloat16* __restrict__ fbf, float* __restrict__ mid)
{
    __shared__ __align__(16) float es_s[4][64];
    __shared__ __align__(16) float h_s[4][4][64];
    __shared__ __align__(16) float w_s[4][4][128];
    __shared__ __align__(16) float g_s[4][4][128];

    int t  = threadIdx.x;
    int wv = t >> 6;   // wave within block
    int j  = t & 63;   // lane

    // per-lane weight columns (registers)
    float W1c[16];
    #pragma unroll
    for (int k = 0; k < 16; ++k) W1c[k] = Wfc1[k * 64 + j];
    float W2a[64], W2b[64];
    #pragma unroll
    for (int k = 0; k < 64; ++k) {
        W2a[k] = Wfc2[k * 128 + j];
        W2b[k] = Wfc2[k * 128 + 64 + j];
    }

    int waveId = blockIdx.x * 4 + wv;
    int stride = NBLK_E * 4 * 4;   // total waves * 4 edges each

    for (int e0 = waveId * 4; e0 < N_EDGES; e0 += stride) {
        // ---- stage edge_scalars for 4 edges (lane j -> edge j/16, elem j%16)
        es_s[wv][j] = edge_scalars[(size_t)e0 * 16 + j];

        int srcs[4], dsts[4];
        #pragma unroll
        for (int e = 0; e < 4; ++e) {
            srcs[e] = edge_src[e0 + e];
            dsts[e] = edge_dst[e0 + e];
        }

        // ---- GEMM1 + silu: h[e][j]
        #pragma unroll
        for (int e = 0; e < 4; ++e) {
            const float4* e4 = (const float4*)&es_s[wv][e * 16];
            float z = 0.f;
            #pragma unroll
            for (int k = 0; k < 4; ++k) {
                float4 v = e4[k];
                z += v.x * W1c[4*k] + v.y * W1c[4*k+1] + v.z * W1c[4*k+2] + v.w * W1c[4*k+3];
            }
            z *= 0.25f;                               // /sqrt(16)
            h_s[wv][e][j] = z / (1.0f + __expf(-z));  // silu
        }

        // ---- GEMM2: w[e][j] and w[e][64+j]
        #pragma unroll
        for (int e = 0; e < 4; ++e) {
            const float4* h4 = (const float4*)h_s[wv][e];
            float za = 0.f, zb = 0.f;
            #pragma unroll
            for (int k = 0; k < 16; ++k) {
                float4 hv = h4[k];
                za += hv.x * W2a[4*k] + hv.y * W2a[4*k+1] + hv.z * W2a[4*k+2] + hv.w * W2a[4*k+3];
                zb += hv.x * W2b[4*k] + hv.y * W2b[4*k+1] + hv.z * W2b[4*k+2] + hv.w * W2b[4*k+3];
            }
            w_s[wv][e][j]      = za * WSCALE;   // folds /8 and /sqrt(10)
            w_s[wv][e][64 + j] = zb * WSCALE;
        }

        // ---- gather g = f[src] (2 bf16 per lane per edge)
        #pragma unroll
        for (int e = 0; e < 4; ++e) {
            unsigned v = *(const unsigned*)&fbf[(size_t)srcs[e] * 128 + 2 * j];
            float lo = __uint_as_float((v & 0xffffu) << 16);
            float hi = __uint_as_float(v & 0xffff0000u);
            *(float2*)&g_s[wv][e][2 * j] = make_float2(lo, hi);
        }

        // ---- features + atomic scatter (256 cols per edge, 4-5 atomics/lane)
        #pragma unroll
        for (int e = 0; e < 4; ++e) {
            const float* wr = w_s[wv][e];
            const float* gr = g_s[wv][e];
            float4 ea = ((const float4*)edge_attr)[e0 + e];
            float y0 = ea.x, y1x = ea.y, y1y = ea.z, y1z = ea.w;
            float* mrow = &mid[(size_t)dsts[e] * 256];

            // col j : eA (j<32) / eD (j>=32)
            float v0;
            if (j < 32) {
                v0 = wr[j] * gr[j] * y0;
            } else {
                int u = j - 32;
                float d = gr[32 + u] * y1x + gr[64 + u] * y1y + gr[96 + u] * y1z;
                v0 = wr[64 + j] * d * INV_SQRT3;   // wr[96+u] = wD[u]
            }
            unsafeAtomicAdd(&mrow[j], v0);

            // col 64+j : eB flat j
            {
                int u = j / 3, m = j - u * 3;
                float ym = (m == 0) ? y1x : ((m == 1) ? y1y : y1z);
                unsafeAtomicAdd(&mrow[64 + j], wr[32 + u] * gr[u] * ym);
            }

            // col 128+j : eB flat 64+j (j<32) / eC flat j-32 (j>=32)
            if (j < 32) {
                int fi = 64 + j; int u = fi / 3, m = fi - u * 3;
                float ym = (m == 0) ? y1x : ((m == 1) ? y1y : y1z);
                unsafeAtomicAdd(&mrow[128 + j], wr[32 + u] * gr[u] * ym);
            } else {
                int fi = j - 32; int u = fi / 3, m = fi - u * 3;
                unsafeAtomicAdd(&mrow[128 + j], wr[64 + u] * gr[32 + m * 32 + u] * y0);
            }

            // col 192+j (j<32) : eC flat 32+j
            if (j < 32) {
                int fi = 32 + j; int u = fi / 3, m = fi - u * 3;
                unsafeAtomicAdd(&mrow[192 + j], wr[64 + u] * gr[32 + m * 32 + u] * y0);
            }

            // col 224+j (j<32) : eC flat 64+j
            if (j < 32) {
                int fi = 64 + j; int u = fi / 3, m = fi - u * 3;
                unsafeAtomicAdd(&mrow[224 + j], wr[64 + u] * gr[32 + m * 32 + u] * y0);
            }
        }
    }
}

// ---------------------------------------------------------------------------
// Kernel D: node post-pass.  Recomputes sc = fctp(x, W_sc) in f32, then
// o = lin2(mid)*attr/8, angle via W_lin3, out = cos(angle)*sc + sin(angle)*conv
// ---------------------------------------------------------------------------
__global__ __launch_bounds__(256) void node_post_kernel(
    const float* __restrict__ mid, const float* __restrict__ node_input,
    const float* __restrict__ node_attr,
    const float* __restrict__ Wsc0, const float* __restrict__ Wsc1,
    const float* __restrict__ W20, const float* __restrict__ W21,
    const float* __restrict__ W3, float* __restrict__ out)
{
    __shared__ float w20[2048], w21[2048], w3[64];
    __shared__ float wsc0[1024], wsc1[1024];
    __shared__ float ms[8 * 256];
    __shared__ float xs[8 * 128];
    int t = threadIdx.x;
    for (int i = t; i < 2048; i += 256) { w20[i] = W20[i]; w21[i] = W21[i]; }
    for (int i = t; i < 1024; i += 256) { wsc0[i] = Wsc0[i]; wsc1[i] = Wsc1[i]; }
    if (t < 64) w3[t] = W3[t];
    int base = blockIdx.x * 8;
    for (int i = t; i < 2048; i += 256) ms[i] = mid[(size_t)base * 256 + i];
    for (int i = t; i < 1024; i += 256) xs[i] = node_input[(size_t)base * 128 + i];
    __syncthreads();

    int nl = t >> 5, w = t & 31;
    int n = base + nl;
    const float* mr = &ms[nl * 256];
    const float* xr = &xs[nl * 128];

    // recompute sc (f32, no bf16 rounding)
    float s0 = 0.f, s1[3] = {0.f, 0.f, 0.f};
    #pragma unroll
    for (int u = 0; u < 32; ++u) {
        float ws = wsc0[u * 32 + w], ws1 = wsc1[u * 32 + w];
        s0 += xr[u] * ws;
        #pragma unroll
        for (int m = 0; m < 3; ++m) s1[m] += xr[32 + u * 3 + m] * ws1;
    }

    // conv = lin2(mid), angle
    float o0 = 0.f, ang = 0.f, o1[3] = {0.f, 0.f, 0.f};
    #pragma unroll
    for (int c = 0; c < 64; ++c) {
        float m0 = mr[c];
        o0  += m0 * w20[c * 32 + w];
        ang += m0 * w3[c];
        float wc = w21[c * 32 + w];
        o1[0] += mr[64 + c * 3 + 0] * wc;
        o1[1] += mr[64 + c * 3 + 1] * wc;
        o1[2] += mr[64 + c * 3 + 2] * wc;
    }
    float attr = node_attr[n];
    float a8 = attr * 0.125f;     // attr / 8
    float as = attr * S32;        // attr / sqrt(32)
    float angle = 0.1f * ang * a8;
    float cs = cosf(angle), sn = sinf(angle);

    out[(size_t)n * 128 + w] = cs * (s0 * as) + sn * (o0 * a8);
    #pragma unroll
    for (int m = 0; m < 3; ++m)
        out[(size_t)n * 128 + 32 + w * 3 + m] = cs * (s1[m] * as) + sn * (o1[m] * a8);
}

// ---------------------------------------------------------------------------
extern "C" void kernel_launch(void* const* d_in, const int* in_sizes, int n_in,
                              void* d_out, int out_size, void* d_ws, size_t ws_size,
                              hipStream_t stream) {
    const float* node_input   = (const float*)d_in[0];
    const float* node_attr    = (const float*)d_in[1];
    const int*   edge_src     = (const int*)d_in[2];
    const int*   edge_dst     = (const int*)d_in[3];
    const float* edge_attr    = (const float*)d_in[4];
    const float* edge_scalars = (const float*)d_in[5];
    const float* W_sc0    = (const float*)d_in[6];
    const float* W_sc1    = (const float*)d_in[7];
    const float* W_lin1_0 = (const float*)d_in[8];
    const float* W_lin1_1 = (const float*)d_in[9];
    const float* W_fc1    = (const float*)d_in[10];
    const float* W_fc2    = (const float*)d_in[11];
    const float* W_lin2_0 = (const float*)d_in[12];
    const float* W_lin2_1 = (const float*)d_in[13];
    const float* W_lin3   = (const float*)d_in[14];
    float* out = (float*)d_out;

    // Workspace: only mid (N*256 f32 = 51.2 MB).
    // fbf (bf16, 12.8 MB) lives in the FIRST HALF of d_out — dead before the
    // post kernel overwrites d_out (kernels are stream-ordered).
    float*          mid = (float*)d_ws;
    __hip_bfloat16* fbf = (__hip_bfloat16*)d_out;

    hipMemsetAsync(mid, 0, (size_t)N_NODES * 256 * 4, stream);
    node_pre_kernel<<<N_NODES / 8, 256, 0, stream>>>(
        node_input, node_attr, W_lin1_0, W_lin1_1, fbf);
    edge_kernel<<<NBLK_E, 256, 0, stream>>>(
        edge_scalars, edge_attr, edge_src, edge_dst, W_fc1, W_fc2, fbf, mid);
    node_post_kernel<<<N_NODES / 8, 256, 0, stream>>>(
        mid, node_input, node_attr, W_sc0, W_sc1, W_lin2_0, W_lin2_1, W_lin3, out);
}